// Round 24
// baseline (378.487 us; speedup 1.0000x reference)
//
#include <hip/hip_runtime.h>
#include <hip/hip_bf16.h>

#define B_ 128
#define T_ 512
#define BIN_ 24
#define D_ 256
#define S_ 128
#define L_ 2
#define BT_ (B_*T_)

typedef __hip_bfloat16 bf16;
typedef __hip_bfloat162 bf162;
typedef __attribute__((ext_vector_type(8))) short bf16x8;
typedef __attribute__((ext_vector_type(4))) short s16x4;
typedef __attribute__((ext_vector_type(4))) float f32x4;

__device__ __forceinline__ float b2f(bf16 x){ return __bfloat162float(x); }
__device__ __forceinline__ bf16 f2b(float x){ return __float2bfloat16(x); }
__device__ __forceinline__ float swish(float v){
  float e = __builtin_amdgcn_exp2f(-1.442695040888963f * v);
  return v * __builtin_amdgcn_rcpf(1.f + e);
}
// async global->LDS, 16B per lane; lds dest is wave-uniform base (+lane*16 by HW)
__device__ __forceinline__ void gld16(const bf16* g, bf16* l){
  __builtin_amdgcn_global_load_lds(
      (const __attribute__((address_space(1))) void*)g,
      (__attribute__((address_space(3))) void*)l, 16, 0, 0);
}

// ---------------- tables: sinusoid PE (scaled) + rope sin/cos ----------------
__global__ void tables_kernel(const float* pe_scale_ptr, float* pe_tab, float* rs, float* rc) {
  int t = blockIdx.x;      // 0..511
  int j = threadIdx.x;     // 64 threads
  float ps = pe_scale_ptr[0];
  const float LOG1E4 = 9.210340371976184f;
  if (j < 64) {
    float inv = expf(-LOG1E4 * (float)j / 64.f);   // rope: 10000^(-2j/128)
    float ang = (float)t * inv;
    rs[t*64 + j] = sinf(ang);
    rc[t*64 + j] = cosf(ang);
  }
  if (j < BIN_) {
    int jj = (j < 12) ? j : (j - 12);
    float inv = expf(-LOG1E4 * (float)jj / 11.f);
    float ang = (float)t * inv;
    pe_tab[t*BIN_ + j] = ps * ((j < 12) ? sinf(ang) : cosf(ang));
  }
}

// ---------------- prep: W1 [2][256][640] -> W1t bf16 [2][640][256]; W2 likewise ----
__global__ __launch_bounds__(256) void prep_kernel(const float* W1, const float* W2,
                                                   bf16* W1t, bf16* W2t) {
  int idx = blockIdx.x*256 + threadIdx.x;
  if (idx < 2*256*640) {
    int l = idx / (256*640); int rem = idx % (256*640);
    int k = rem / 640; int n = rem % 640;
    W1t[(size_t)l*640*256 + n*256 + k] = f2b(W1[idx]);
  }
  if (idx < 2*256*256) {
    int l = idx >> 16; int rem = idx & 65535;
    int k = rem >> 8; int n = rem & 255;
    W2t[(size_t)l*65536 + n*256 + k] = f2b(W2[idx]);
  }
}

// ---------------- init: zero rms1 + pooled_raw ----------------
__global__ __launch_bounds__(256) void init_kernel(float* rms1, float* pooled_raw) {
  int i = blockIdx.x*256 + threadIdx.x;
  if (i < BT_) rms1[i] = 0.f;
  if (i < B_*D_) pooled_raw[i] = 0.f;
}

// ---------------- embed: hb = swish((x+pe)@W_in+b_in) (bf16); rms0[row]=sum(h^2) ---
__global__ __launch_bounds__(256) void embed_kernel(const float* x, const float* pe_tab,
                const float* W_in, const float* b_in, float* rms0, bf16* hb) {
  __shared__ float xr[8][BIN_];
  __shared__ float wsum[4][8];
  int tid = threadIdx.x;
  int row0 = blockIdx.x * 8;
  if (tid < 8*BIN_) {
    int r = tid / BIN_, k = tid % BIN_;
    int row = row0 + r;
    int t = row & (T_-1);
    xr[r][k] = x[(size_t)row*BIN_ + k] + pe_tab[t*BIN_ + k];
  }
  __syncthreads();
  int d = tid;
  float bi = b_in[d];
  float acc[8];
  #pragma unroll
  for (int r=0;r<8;r++) acc[r]=bi;
  #pragma unroll
  for (int k=0;k<BIN_;k++){
    float w = W_in[k*D_ + d];
    #pragma unroll
    for (int r=0;r<8;r++) acc[r] += xr[r][k]*w;
  }
  float sq[8];
  #pragma unroll
  for (int r=0;r<8;r++){
    float v = swish(acc[r]);
    hb[(size_t)(row0+r)*D_ + d] = f2b(v);
    sq[r] = v*v;
  }
  #pragma unroll
  for (int off=1; off<64; off<<=1)
    #pragma unroll
    for (int r=0;r<8;r++) sq[r] += __shfl_xor(sq[r], off);
  if ((tid&63)==0)
    #pragma unroll
    for (int r=0;r<8;r++) wsum[tid>>6][r] = sq[r];
  __syncthreads();
  if (tid < 8) rms0[row0+tid] = wsum[0][tid]+wsum[1][tid]+wsum[2][tid]+wsum[3][tid];
}

// ---------------- gemm1 (MFMA): [u|Vt_g|base] = swish(rms(h)@W1+b1)
// Staging via global_load_lds width=16 into LINEAR [128][64] LDS tiles with
// XOR-chunk swizzle. ALL epilogue outputs bounce through the Ovl overlay.
__global__ __launch_bounds__(256) void gemm1_mfma(const bf16* A, const bf16* Bt,
      const float* bias, const float* rmsraw, const float* norm_scale, int l,
      bf16* u, bf16* Vtg, bf16* basebuf) {
  __shared__ char smem[34816];
  bf16* As  = (bf16*)smem;            // [128][64] linear (swizzled content)
  bf16* Bs  = (bf16*)(smem + 16384);  // [128][64]
  bf16* Ovl = (bf16*)smem;            // [128][136] epilogue overlay

  int tid = threadIdx.x;
  int w = tid>>6, lane = tid&63, r = lane&15, g = lane>>4;
  int wr = w>>1, wc = w&1;
  int dd = blockIdx.x; int xcd = dd&7, slot = dd>>3;
  int panel = xcd*64 + slot/5; int bx = slot%5;
  int row0 = panel*128, col0 = bx*128;

  int trl = 8*w + (lane>>3);
  int tcg = ((lane&7) ^ ((lane>>3)&7)) * 8;

  f32x4 acc[4][4];
  #pragma unroll
  for (int i=0;i<4;i++)
    #pragma unroll
    for (int j=0;j<4;j++) acc[i][j] = (f32x4){0.f,0.f,0.f,0.f};

  for (int k0=0; k0<D_; k0+=64) {
    #pragma unroll
    for (int i=0;i<4;i++){
      int tr = 32*i + trl;
      gld16(A  + (size_t)(row0+tr)*D_ + k0 + tcg, As + (32*i + 8*w)*64);
      gld16(Bt + (size_t)(col0+tr)*D_ + k0 + tcg, Bs + (32*i + 8*w)*64);
    }
    __syncthreads();
    #pragma unroll
    for (int kk=0; kk<2; kk++){
      bf16x8 a[4], b[4];
      #pragma unroll
      for (int i=0;i<4;i++){
        int ch = ((kk*4 + g) ^ (r&7)) * 8;
        a[i] = *(const bf16x8*)(As + (64*wr+16*i+r)*64 + ch);
        b[i] = *(const bf16x8*)(Bs + (64*wc+16*i+r)*64 + ch);
      }
      #pragma unroll
      for (int i=0;i<4;i++)
        #pragma unroll
        for (int j=0;j<4;j++)
          acc[i][j] = __builtin_amdgcn_mfma_f32_16x16x32_bf16(a[i], b[j], acc[i][j], 0,0,0);
    }
    __syncthreads();
  }

  float ns = norm_scale[l];
  #pragma unroll
  for (int i=0;i<4;i++){
    size_t grow0 = row0 + 64*wr + 16*i + 4*g;
    float4 rv = *(const float4*)(rmsraw + grow0);
    float sc[4];
    sc[0] = rsqrtf(rv.x*(1.f/D_) + 1e-6f) * ns;
    sc[1] = rsqrtf(rv.y*(1.f/D_) + 1e-6f) * ns;
    sc[2] = rsqrtf(rv.z*(1.f/D_) + 1e-6f) * ns;
    sc[3] = rsqrtf(rv.w*(1.f/D_) + 1e-6f) * ns;
    #pragma unroll
    for (int j=0;j<4;j++){
      int gcol = col0 + 64*wc + 16*j + r;
      float bv = bias[gcol];
      if (bx == 2 || bx == 3) {
        #pragma unroll
        for (int reg=0; reg<4; reg++){
          float v = swish(acc[i][j][reg]*sc[reg] + bv);
          Ovl[(64*wc+16*j+r)*136 + (64*wr+16*i+4*g+reg)] = f2b(v);
        }
      } else {
        #pragma unroll
        for (int reg=0; reg<4; reg++){
          float v = swish(acc[i][j][reg]*sc[reg] + bv);
          Ovl[(64*wr+16*i+4*g+reg)*136 + (64*wc+16*j+r)] = f2b(v);
        }
      }
    }
  }

  __syncthreads();
  if (bx == 2 || bx == 3) {
    size_t bb = row0 >> 9;
    int mg = row0 & 511;
    #pragma unroll
    for (int c=0;c<8;c++){
      int chunk = c*256 + tid;
      int e = chunk >> 4, mloc = (chunk & 15)*8;
      *(bf16x8*)(Vtg + bb*131072 + (size_t)(col0-256+e)*T_ + mg + mloc) =
        *(const bf16x8*)(Ovl + e*136 + mloc);
    }
  } else {
    #pragma unroll
    for (int c=0;c<8;c++){
      int chunk = c*256 + tid;
      int lr = chunk >> 4, lc = (chunk & 15)*8;
      bf16x8 v = *(const bf16x8*)(Ovl + lr*136 + lc);
      if (bx < 2)
        *(bf16x8*)(u + (size_t)(row0+lr)*D_ + col0 + lc) = v;
      else
        *(bf16x8*)(basebuf + (size_t)(row0+lr)*S_ + lc) = v;
    }
  }
}

// ---------------- qk: rope(base*gamma+beta) for q and k ----------------
__global__ __launch_bounds__(256) void qk_kernel(const bf16* basebuf, const float* gamma, const float* beta,
      int l, const float* rs, const float* rc, bf16* q, bf16* k) {
  int tid = threadIdx.x;
  int j = tid & 127;
  size_t row = (size_t)blockIdx.x*2 + (tid>>7);
  int t = (int)(row & (T_-1));
  int j2 = j ^ 64;
  float v0 = b2f(basebuf[row*S_ + j]);
  float v1 = b2f(basebuf[row*S_ + j2]);
  int jm = j & 63;
  float sn = rs[t*64 + jm], cs = rc[t*64 + jm];
  float sgn = (j < 64) ? -1.f : 1.f;
  const float* g  = gamma + l*2*S_;
  const float* bt = beta  + l*2*S_;
  float xq = v0*g[j]      + bt[j];
  float pq = v1*g[j2]     + bt[j2];
  q[row*S_ + j] = f2b(xq*cs + sgn*pq*sn);
  float xk = v0*g[S_+j]   + bt[S_+j];
  float pk = v1*g[S_+j2]  + bt[S_+j2];
  k[row*S_ + j] = f2b(xk*cs + sgn*pk*sn);
}

// ---------------- attn+gemm2 fused: hb += (u ⊙ (relu(qk^T/512)^2 @ v)) @ W2 + b2
// Retiled for occupancy: q-tile 64 rows, KV-tile 32 rows. LDS 33.8KB, regs ~80
// -> target 3 blocks/CU (24 waves). All fragment mappings = verified 16x16 set.
__global__ __launch_bounds__(512, 6) void attn_gemm2_fused(const bf16* q, const bf16* k,
      const bf16* Vtg, const bf16* u, const bf16* W2t, const float* bias,
      int mode, float* rms1, float* pooled_raw, float* outb, bf16* hb) {
  __shared__ char smem[33792];
  bf16* Ks = (bf16*)smem;            // [32][128] linear, swizzled (c^=row&7)
  bf16* Vt = (bf16*)(smem + 8192);   // [256 e][32 m], chunks swizzled (c^=e&3)
  bf16* Ps = (bf16*)(smem + 24576);  // [64][40]
  bf16* Os = (bf16*)smem;            // [64][264] (gemm2 phase overlay)

  int tid = threadIdx.x;
  int w = tid >> 6, l = tid & 63;
  int r = l & 15, g = l >> 4;
  int wq = w & 3, nfh = w >> 2;      // QK^T: rows 16wq.., kv-col half nfh
  int rgp2 = w & 1, eh2 = w >> 1;    // PV: rows 32rgp2.., e-range 64*eh2..
  int xcd = blockIdx.x & 7, j0 = blockIdx.x >> 3;
  int b  = xcd*16 + (j0 >> 3);
  int nt = j0 & 7;
  size_t rowbase = (size_t)b * T_;
  int n0 = nt * 64;

  bf16x8 qf[4];
  const bf16* qrow = q + (rowbase + n0 + 16*wq + r) * S_ + g*8;
  #pragma unroll
  for (int kk=0; kk<4; kk++) qf[kk] = *(const bf16x8*)(qrow + kk*32);

  f32x4 oacc[8];   // [rr*4+ef]: rows 32rgp2+16rr, e-cols 16*(4eh2+ef)
  #pragma unroll
  for (int i=0;i<8;i++) oacc[i] = (f32x4){0.f,0.f,0.f,0.f};

  for (int m0 = 0; m0 < T_; m0 += 32) {
    // ---- K stage: 512 chunks (1/thread) ----
    {
      int row = tid >> 4, c = tid & 15;
      gld16(k + (rowbase + m0 + row)*S_ + ((c ^ (row&7)) << 3), Ks + w*512);
    }
    // ---- V stage: 1024 chunks (2/thread) ----
    #pragma unroll
    for (int i=0;i<2;i++){
      int chunk = i*512 + tid;
      int e = chunk >> 2, c = chunk & 3;
      gld16(Vtg + (size_t)b*131072 + (size_t)e*T_ + m0 + ((c ^ (e&3)) << 3),
            Vt + (i*512 + w*64)*8);
    }
    __syncthreads();

    // ---- QK^T: rows 16wq..+15 x kv 16nfh..+15 (4 MFMA) ----
    __builtin_amdgcn_s_setprio(1);
    {
      f32x4 sacc = (f32x4){0.f,0.f,0.f,0.f};
      #pragma unroll
      for (int kk=0; kk<4; kk++){
        int ch = ((kk*4 + g) ^ (r&7)) * 8;
        bf16x8 kf = *(const bf16x8*)(Ks + (16*nfh + r)*128 + ch);
        sacc = __builtin_amdgcn_mfma_f32_16x16x32_bf16(qf[kk], kf, sacc, 0,0,0);
      }
      #pragma unroll
      for (int reg=0; reg<4; reg++){
        float t = fmaxf(sacc[reg] * (1.f/512.f), 0.f);
        Ps[(16*wq + 4*g + reg)*40 + 16*nfh + r] = f2b(t*t);
      }
    }
    __builtin_amdgcn_s_setprio(0);
    __syncthreads();   // Ps cross-wave

    // ---- PV: rows 32rgp2..+31 x e 64*eh2..+63 (8 MFMA, k=32 single step) ----
    __builtin_amdgcn_s_setprio(1);
    {
      bf16x8 pa0 = *(const bf16x8*)(Ps + (32*rgp2      + r)*40 + g*8);
      bf16x8 pa1 = *(const bf16x8*)(Ps + (32*rgp2 + 16 + r)*40 + g*8);
      #pragma unroll
      for (int ef=0; ef<4; ef++){
        int e = 16*(4*eh2 + ef) + r;
        bf16x8 vb = *(const bf16x8*)(Vt + e*32 + ((g ^ (e&3)) << 3));
        oacc[ef]   = __builtin_amdgcn_mfma_f32_16x16x32_bf16(pa0, vb, oacc[ef],   0,0,0);
        oacc[4+ef] = __builtin_amdgcn_mfma_f32_16x16x32_bf16(pa1, vb, oacc[4+ef], 0,0,0);
      }
    }
    __builtin_amdgcn_s_setprio(0);
    __syncthreads();
  }

  // ---- Phase 2: Os = PV, coalesced u-multiply ----
  size_t growbase = rowbase + n0;
  #pragma unroll
  for (int rr=0; rr<2; rr++)
    #pragma unroll
    for (int ef=0; ef<4; ef++)
      #pragma unroll
      for (int reg=0; reg<4; reg++)
        Os[(32*rgp2 + 16*rr + 4*g + reg)*264 + 16*(4*eh2+ef) + r] = f2b(oacc[rr*4+ef][reg]);
  __syncthreads();
  #pragma unroll
  for (int i=0;i<4;i++){
    int chunk = i*512 + tid;
    int row = chunk >> 5, c = chunk & 31;
    bf16x8 uvv = *(const bf16x8*)(u + (growbase + row)*D_ + c*8);
    bf16x8 ov  = *(const bf16x8*)(Os + row*264 + c*8);
    bf16x8 res;
    #pragma unroll
    for (int e=0;e<8;e++)
      ((bf16*)&res)[e] = f2b(b2f(((bf16*)&ov)[e]) * b2f(((bf16*)&uvv)[e]));
    *(bf16x8*)(Os + row*264 + c*8) = res;
  }
  __syncthreads();

  // ---- Os @ W2: kc-outer; wave w owns cols {16w..+15} and {128+16w..+15} ----
  f32x4 acc2[2][4];
  #pragma unroll
  for (int c2=0;c2<2;c2++)
    #pragma unroll
    for (int i=0;i<4;i++) acc2[c2][i] = (f32x4){0.f,0.f,0.f,0.f};
  __builtin_amdgcn_s_setprio(1);
  #pragma unroll
  for (int kc=0; kc<8; kc++){
    bf16x8 a0[4];
    #pragma unroll
    for (int i=0;i<4;i++)
      a0[i] = *(const bf16x8*)(Os + (16*i + r)*264 + kc*32 + g*8);
    #pragma unroll
    for (int chf=0; chf<2; chf++){
      bf16x8 wfr = *(const bf16x8*)(W2t + (size_t)(128*chf + 16*w + r)*256 + kc*32 + g*8);
      #pragma unroll
      for (int i=0;i<4;i++)
        acc2[chf][i] = __builtin_amdgcn_mfma_f32_16x16x32_bf16(a0[i], wfr, acc2[chf][i], 0,0,0);
    }
  }
  __builtin_amdgcn_s_setprio(0);

  // ---- epilogue (wave-owns-cols): residual RMW on bf16 hb ----
  #pragma unroll
  for (int chf=0; chf<2; chf++){
    int col = 128*chf + 16*w + r;
    float bv = bias[col];
    if (mode == 0) {
      #pragma unroll
      for (int i=0;i<4;i++){
        #pragma unroll
        for (int reg=0; reg<4; reg++){
          size_t row = growbase + 16*i + 4*g + reg;
          float hv = b2f(hb[row*D_ + col]) + acc2[chf][i][reg] + bv;
          hb[row*D_ + col] = f2b(hv);
          float ssum = hv*hv;
          ssum += __shfl_xor(ssum,1); ssum += __shfl_xor(ssum,2);
          ssum += __shfl_xor(ssum,4); ssum += __shfl_xor(ssum,8);
          if (r == 0) atomicAdd(rms1 + row, ssum);
        }
      }
    } else {
      float psum = 0.f;
      #pragma unroll
      for (int i=0;i<4;i++){
        #pragma unroll
        for (int reg=0; reg<4; reg++){
          size_t row = growbase + 16*i + 4*g + reg;
          float hv = b2f(hb[row*D_ + col]) + acc2[chf][i][reg] + bv;
          outb[row*D_ + col] = hv;
          float cv = fmaxf(hv, 1e-6f);
          psum += cv*cv*cv;
        }
      }
      psum += __shfl_xor(psum,16); psum += __shfl_xor(psum,32);
      if (g == 0) atomicAdd(pooled_raw + b*D_ + col, psum);
    }
  }
}

// ---------------- emb: pooled=cbrt(raw/T); emb = norm(pooled@We+be) ----------------
__global__ __launch_bounds__(256) void emb_kernel(const float* pooled_raw, const float* We,
      const float* be, float* out) {
  __shared__ float pr[D_];
  __shared__ float red[256];
  int b = blockIdx.x, j = threadIdx.x;
  pr[j] = cbrtf(pooled_raw[b*D_+j] * (1.f/T_));
  __syncthreads();
  float acc = be[j];
  for (int kk=0;kk<D_;kk++) acc += pr[kk]*We[kk*D_+j];
  red[j] = acc*acc;
  __syncthreads();
  for (int off=128; off>0; off>>=1){
    if (j<off) red[j]+=red[j+off];
    __syncthreads();
  }
  out[b*D_+j] = acc * rsqrtf(red[0]);
}

extern "C" void kernel_launch(void* const* d_in, const int* in_sizes, int n_in,
                              void* d_out, int out_size, void* d_ws, size_t ws_size,
                              hipStream_t stream) {
  const float* x         = (const float*)d_in[0];
  const float* pe_scale  = (const float*)d_in[1];
  const float* W_in      = (const float*)d_in[2];
  const float* b_in      = (const float*)d_in[3];
  const float* norm_scale= (const float*)d_in[4];
  const float* W1        = (const float*)d_in[5];
  const float* b1        = (const float*)d_in[6];
  const float* gamma     = (const float*)d_in[7];
  const float* beta      = (const float*)d_in[8];
  const float* W2        = (const float*)d_in[9];
  const float* b2        = (const float*)d_in[10];
  const float* We        = (const float*)d_in[11];
  const float* be        = (const float*)d_in[12];

  char* ws = (char*)d_ws;
  bf16*  hb      = (bf16*)(ws);                       // 33,554,432 B (bf16 residual)
  bf16*  u       = (bf16*)(ws + 33554432);            // 33,554,432 B
  bf16*  Vtg     = (bf16*)(ws + 67108864);            // 33,554,432 B
  bf16*  basebuf = (bf16*)(ws + 100663296);           // 16,777,216 B
  bf16*  q       = (bf16*)(ws + 117440512);           // 16,777,216 B
  bf16*  kbuf    = (bf16*)(ws + 134217728);           // 16,777,216 B
  float* pe_tab  = (float*)(ws + 150994944);          //     49,152 B
  float* rs_tab  = (float*)(ws + 151044096);          //    131,072 B
  float* rc_tab  = (float*)(ws + 151175168);          //    131,072 B
  float* pooled_raw = (float*)(ws + 151306240);       //    131,072 B
  float* rms0    = (float*)(ws + 151437312);          //    262,144 B
  float* rms1    = (float*)(ws + 151699456);          //    262,144 B
  bf16*  W1t     = (bf16*)(ws + 151961600);           //    655,360 B
  bf16*  W2t     = (bf16*)(ws + 152616960);           //    262,144 B

  tables_kernel<<<T_, 64, 0, stream>>>(pe_scale, pe_tab, rs_tab, rc_tab);
  prep_kernel<<<1280, 256, 0, stream>>>(W1, W2, W1t, W2t);
  init_kernel<<<BT_/256, 256, 0, stream>>>(rms1, pooled_raw);
  embed_kernel<<<BT_/8, 256, 0, stream>>>(x, pe_tab, W_in, b_in, rms0, hb);
  float* outb = (float*)d_out + B_*D_;
  for (int l=0; l<L_; l++) {
    gemm1_mfma<<<BT_/128*5, 256, 0, stream>>>(hb, W1t + (size_t)l*640*D_, b1 + l*640,
        l ? rms1 : rms0, norm_scale, l, u, Vtg, basebuf);
    qk_kernel<<<BT_/2, 256, 0, stream>>>(basebuf, gamma, beta, l, rs_tab, rc_tab, q, kbuf);
    attn_gemm2_fused<<<B_*8, 512, 0, stream>>>(q, kbuf, Vtg, u,
        W2t + (size_t)l*D_*D_, b2 + l*D_, l, rms1, pooled_raw, outb, hb);
  }
  emb_kernel<<<B_, 256, 0, stream>>>(pooled_raw, We, be, (float*)d_out);
}

// Round 25
// 331.577 us; speedup vs baseline: 1.1415x; 1.1415x over previous
//
#include <hip/hip_runtime.h>
#include <hip/hip_bf16.h>

#define B_ 128
#define T_ 512
#define BIN_ 24
#define D_ 256
#define S_ 128
#define L_ 2
#define BT_ (B_*T_)

typedef __hip_bfloat16 bf16;
typedef __hip_bfloat162 bf162;
typedef __attribute__((ext_vector_type(8))) short bf16x8;
typedef __attribute__((ext_vector_type(4))) short s16x4;
typedef __attribute__((ext_vector_type(4))) float f32x4;

__device__ __forceinline__ float b2f(bf16 x){ return __bfloat162float(x); }
__device__ __forceinline__ bf16 f2b(float x){ return __float2bfloat16(x); }
__device__ __forceinline__ float swish(float v){
  float e = __builtin_amdgcn_exp2f(-1.442695040888963f * v);
  return v * __builtin_amdgcn_rcpf(1.f + e);
}
// async global->LDS, 16B per lane; lds dest is wave-uniform base (+lane*16 by HW)
__device__ __forceinline__ void gld16(const bf16* g, bf16* l){
  __builtin_amdgcn_global_load_lds(
      (const __attribute__((address_space(1))) void*)g,
      (__attribute__((address_space(3))) void*)l, 16, 0, 0);
}

// ---------------- tables: sinusoid PE (scaled) + rope sin/cos ----------------
__global__ void tables_kernel(const float* pe_scale_ptr, float* pe_tab, float* rs, float* rc) {
  int t = blockIdx.x;      // 0..511
  int j = threadIdx.x;     // 64 threads
  float ps = pe_scale_ptr[0];
  const float LOG1E4 = 9.210340371976184f;
  if (j < 64) {
    float inv = expf(-LOG1E4 * (float)j / 64.f);   // rope: 10000^(-2j/128)
    float ang = (float)t * inv;
    rs[t*64 + j] = sinf(ang);
    rc[t*64 + j] = cosf(ang);
  }
  if (j < BIN_) {
    int jj = (j < 12) ? j : (j - 12);
    float inv = expf(-LOG1E4 * (float)jj / 11.f);
    float ang = (float)t * inv;
    pe_tab[t*BIN_ + j] = ps * ((j < 12) ? sinf(ang) : cosf(ang));
  }
}

// ---------------- prep: W1 [2][256][640] -> W1t bf16 [2][640][256]; W2 likewise ----
__global__ __launch_bounds__(256) void prep_kernel(const float* W1, const float* W2,
                                                   bf16* W1t, bf16* W2t) {
  int idx = blockIdx.x*256 + threadIdx.x;
  if (idx < 2*256*640) {
    int l = idx / (256*640); int rem = idx % (256*640);
    int k = rem / 640; int n = rem % 640;
    W1t[(size_t)l*640*256 + n*256 + k] = f2b(W1[idx]);
  }
  if (idx < 2*256*256) {
    int l = idx >> 16; int rem = idx & 65535;
    int k = rem >> 8; int n = rem & 255;
    W2t[(size_t)l*65536 + n*256 + k] = f2b(W2[idx]);
  }
}

// ---------------- init: zero rms1 + pooled_raw ----------------
__global__ __launch_bounds__(256) void init_kernel(float* rms1, float* pooled_raw) {
  int i = blockIdx.x*256 + threadIdx.x;
  if (i < BT_) rms1[i] = 0.f;
  if (i < B_*D_) pooled_raw[i] = 0.f;
}

// ---------------- embed: hb = swish((x+pe)@W_in+b_in) (bf16); rms0[row]=sum(h^2) ---
__global__ __launch_bounds__(256) void embed_kernel(const float* x, const float* pe_tab,
                const float* W_in, const float* b_in, float* rms0, bf16* hb) {
  __shared__ float xr[8][BIN_];
  __shared__ float wsum[4][8];
  int tid = threadIdx.x;
  int row0 = blockIdx.x * 8;
  if (tid < 8*BIN_) {
    int r = tid / BIN_, k = tid % BIN_;
    int row = row0 + r;
    int t = row & (T_-1);
    xr[r][k] = x[(size_t)row*BIN_ + k] + pe_tab[t*BIN_ + k];
  }
  __syncthreads();
  int d = tid;
  float bi = b_in[d];
  float acc[8];
  #pragma unroll
  for (int r=0;r<8;r++) acc[r]=bi;
  #pragma unroll
  for (int k=0;k<BIN_;k++){
    float w = W_in[k*D_ + d];
    #pragma unroll
    for (int r=0;r<8;r++) acc[r] += xr[r][k]*w;
  }
  float sq[8];
  #pragma unroll
  for (int r=0;r<8;r++){
    float v = swish(acc[r]);
    hb[(size_t)(row0+r)*D_ + d] = f2b(v);
    sq[r] = v*v;
  }
  #pragma unroll
  for (int off=1; off<64; off<<=1)
    #pragma unroll
    for (int r=0;r<8;r++) sq[r] += __shfl_xor(sq[r], off);
  if ((tid&63)==0)
    #pragma unroll
    for (int r=0;r<8;r++) wsum[tid>>6][r] = sq[r];
  __syncthreads();
  if (tid < 8) rms0[row0+tid] = wsum[0][tid]+wsum[1][tid]+wsum[2][tid]+wsum[3][tid];
}

// ---------------- gemm1 (MFMA): [u|Vt_g|base] = swish(rms(h)@W1+b1)
// Staging via global_load_lds width=16 into LINEAR [128][64] LDS tiles with
// XOR-chunk swizzle. ALL epilogue outputs bounce through the Ovl overlay.
__global__ __launch_bounds__(256) void gemm1_mfma(const bf16* A, const bf16* Bt,
      const float* bias, const float* rmsraw, const float* norm_scale, int l,
      bf16* u, bf16* Vtg, bf16* basebuf) {
  __shared__ char smem[34816];
  bf16* As  = (bf16*)smem;            // [128][64] linear (swizzled content)
  bf16* Bs  = (bf16*)(smem + 16384);  // [128][64]
  bf16* Ovl = (bf16*)smem;            // [128][136] epilogue overlay

  int tid = threadIdx.x;
  int w = tid>>6, lane = tid&63, r = lane&15, g = lane>>4;
  int wr = w>>1, wc = w&1;
  int dd = blockIdx.x; int xcd = dd&7, slot = dd>>3;
  int panel = xcd*64 + slot/5; int bx = slot%5;
  int row0 = panel*128, col0 = bx*128;

  int trl = 8*w + (lane>>3);
  int tcg = ((lane&7) ^ ((lane>>3)&7)) * 8;

  f32x4 acc[4][4];
  #pragma unroll
  for (int i=0;i<4;i++)
    #pragma unroll
    for (int j=0;j<4;j++) acc[i][j] = (f32x4){0.f,0.f,0.f,0.f};

  for (int k0=0; k0<D_; k0+=64) {
    #pragma unroll
    for (int i=0;i<4;i++){
      int tr = 32*i + trl;
      gld16(A  + (size_t)(row0+tr)*D_ + k0 + tcg, As + (32*i + 8*w)*64);
      gld16(Bt + (size_t)(col0+tr)*D_ + k0 + tcg, Bs + (32*i + 8*w)*64);
    }
    __syncthreads();
    #pragma unroll
    for (int kk=0; kk<2; kk++){
      bf16x8 a[4], b[4];
      #pragma unroll
      for (int i=0;i<4;i++){
        int ch = ((kk*4 + g) ^ (r&7)) * 8;
        a[i] = *(const bf16x8*)(As + (64*wr+16*i+r)*64 + ch);
        b[i] = *(const bf16x8*)(Bs + (64*wc+16*i+r)*64 + ch);
      }
      #pragma unroll
      for (int i=0;i<4;i++)
        #pragma unroll
        for (int j=0;j<4;j++)
          acc[i][j] = __builtin_amdgcn_mfma_f32_16x16x32_bf16(a[i], b[j], acc[i][j], 0,0,0);
    }
    __syncthreads();
  }

  float ns = norm_scale[l];
  #pragma unroll
  for (int i=0;i<4;i++){
    size_t grow0 = row0 + 64*wr + 16*i + 4*g;
    float4 rv = *(const float4*)(rmsraw + grow0);
    float sc[4];
    sc[0] = rsqrtf(rv.x*(1.f/D_) + 1e-6f) * ns;
    sc[1] = rsqrtf(rv.y*(1.f/D_) + 1e-6f) * ns;
    sc[2] = rsqrtf(rv.z*(1.f/D_) + 1e-6f) * ns;
    sc[3] = rsqrtf(rv.w*(1.f/D_) + 1e-6f) * ns;
    #pragma unroll
    for (int j=0;j<4;j++){
      int gcol = col0 + 64*wc + 16*j + r;
      float bv = bias[gcol];
      if (bx == 2 || bx == 3) {
        #pragma unroll
        for (int reg=0; reg<4; reg++){
          float v = swish(acc[i][j][reg]*sc[reg] + bv);
          Ovl[(64*wc+16*j+r)*136 + (64*wr+16*i+4*g+reg)] = f2b(v);
        }
      } else {
        #pragma unroll
        for (int reg=0; reg<4; reg++){
          float v = swish(acc[i][j][reg]*sc[reg] + bv);
          Ovl[(64*wr+16*i+4*g+reg)*136 + (64*wc+16*j+r)] = f2b(v);
        }
      }
    }
  }

  __syncthreads();
  if (bx == 2 || bx == 3) {
    size_t bb = row0 >> 9;
    int mg = row0 & 511;
    #pragma unroll
    for (int c=0;c<8;c++){
      int chunk = c*256 + tid;
      int e = chunk >> 4, mloc = (chunk & 15)*8;
      *(bf16x8*)(Vtg + bb*131072 + (size_t)(col0-256+e)*T_ + mg + mloc) =
        *(const bf16x8*)(Ovl + e*136 + mloc);
    }
  } else {
    #pragma unroll
    for (int c=0;c<8;c++){
      int chunk = c*256 + tid;
      int lr = chunk >> 4, lc = (chunk & 15)*8;
      bf16x8 v = *(const bf16x8*)(Ovl + lr*136 + lc);
      if (bx < 2)
        *(bf16x8*)(u + (size_t)(row0+lr)*D_ + col0 + lc) = v;
      else
        *(bf16x8*)(basebuf + (size_t)(row0+lr)*S_ + lc) = v;
    }
  }
}

// ---------------- qk: rope(base*gamma+beta) for q and k ----------------
__global__ __launch_bounds__(256) void qk_kernel(const bf16* basebuf, const float* gamma, const float* beta,
      int l, const float* rs, const float* rc, bf16* q, bf16* k) {
  int tid = threadIdx.x;
  int j = tid & 127;
  size_t row = (size_t)blockIdx.x*2 + (tid>>7);
  int t = (int)(row & (T_-1));
  int j2 = j ^ 64;
  float v0 = b2f(basebuf[row*S_ + j]);
  float v1 = b2f(basebuf[row*S_ + j2]);
  int jm = j & 63;
  float sn = rs[t*64 + jm], cs = rc[t*64 + jm];
  float sgn = (j < 64) ? -1.f : 1.f;
  const float* g  = gamma + l*2*S_;
  const float* bt = beta  + l*2*S_;
  float xq = v0*g[j]      + bt[j];
  float pq = v1*g[j2]     + bt[j2];
  q[row*S_ + j] = f2b(xq*cs + sgn*pq*sn);
  float xk = v0*g[S_+j]   + bt[S_+j];
  float pk = v1*g[S_+j2]  + bt[S_+j2];
  k[row*S_ + j] = f2b(xk*cs + sgn*pk*sn);
}

// ---------------- attn+gemm2 fused: hb += (u ⊙ (relu(qk^T/512)^2 @ v)) @ W2 + b2
// Residual stream bf16 (hb). Phase 1: gld16 staging, swizzled Ks/Vt; PV re-split
// (rows 32rgp x e-half 128eh). Phase 2: wave-owns-cols, W2 frags in registers.
__global__ __launch_bounds__(512, 4) void attn_gemm2_fused(const bf16* q, const bf16* k,
      const bf16* Vtg, const bf16* u, const bf16* W2t, const float* bias,
      int mode, float* rms1, float* pooled_raw, float* outb, bf16* hb) {
  __shared__ char smem[67584];
  bf16* Ks = (bf16*)smem;            // [64][128] linear, swizzled content
  bf16* Vt = (bf16*)(smem + 16384);  // [256][64], 16B chunks XOR-swizzled by e&7
  bf16* Ps = (bf16*)(smem + 49152);  // [128][72]
  bf16* Os = (bf16*)smem;            // [128][264] (gemm2 phase, overlays all)

  int tid = threadIdx.x;
  int w = tid >> 6, l = tid & 63;
  int r = l & 15, g = l >> 4;
  int rgp = w & 3, eh = w >> 2;
  int xcd = blockIdx.x & 7, j0 = blockIdx.x >> 3;
  int b  = xcd*16 + (j0 >> 2);
  int nt = j0 & 3;
  size_t rowbase = (size_t)b * T_;
  int n0 = nt * 128;

  bf16x8 qf[4];
  const bf16* qrow = q + (rowbase + n0 + 16*w + r) * S_ + g*8;
  #pragma unroll
  for (int kk=0; kk<4; kk++) qf[kk] = *(const bf16x8*)(qrow + kk*32);

  f32x4 oacc[16];   // [rr*8+ef]: rows 32rgp+16rr, e-cols 16(8eh+ef)
  #pragma unroll
  for (int i=0;i<16;i++) oacc[i] = (f32x4){0.f,0.f,0.f,0.f};

  for (int m0 = 0; m0 < T_; m0 += 64) {
    #pragma unroll
    for (int i=0;i<2;i++){
      int chunk = i*512 + w*64 + l;
      int row = chunk >> 4, c = chunk & 15;
      gld16(k + (rowbase + m0 + row)*S_ + ((c ^ (row&7)) << 3),
            Ks + (i*512 + w*64)*8);
    }
    #pragma unroll
    for (int i=0;i<4;i++){
      int chunk = i*512 + w*64 + l;
      int e = chunk >> 3, c = chunk & 7;
      gld16(Vtg + (size_t)b*131072 + (size_t)e*T_ + m0 + ((c ^ (e&7)) << 3),
            Vt + (i*512 + w*64)*8);
    }
    __syncthreads();

    // ---- QK^T ----
    __builtin_amdgcn_s_setprio(1);
    #pragma unroll
    for (int nf=0; nf<4; nf++){
      f32x4 sacc = (f32x4){0.f,0.f,0.f,0.f};
      #pragma unroll
      for (int kk=0; kk<4; kk++){
        int ch = ((kk*4 + g) ^ (r&7)) * 8;
        bf16x8 kf = *(const bf16x8*)(Ks + (16*nf + r)*128 + ch);
        sacc = __builtin_amdgcn_mfma_f32_16x16x32_bf16(qf[kk], kf, sacc, 0,0,0);
      }
      #pragma unroll
      for (int reg=0; reg<4; reg++){
        float t = fmaxf(sacc[reg] * (1.f/512.f), 0.f);
        Ps[(16*w + 4*g + reg)*72 + 16*nf + r] = f2b(t*t);
      }
    }
    __builtin_amdgcn_s_setprio(0);
    __syncthreads();   // Ps cross-wave

    // ---- PV: wave = rows 32rgp..+31 x e-cols 128eh..+127 ----
    __builtin_amdgcn_s_setprio(1);
    #pragma unroll
    for (int ks=0; ks<2; ks++){
      bf16x8 pa0 = *(const bf16x8*)(Ps + (32*rgp      + r)*72 + ks*32 + g*8);
      bf16x8 pa1 = *(const bf16x8*)(Ps + (32*rgp + 16 + r)*72 + ks*32 + g*8);
      #pragma unroll
      for (int ef=0; ef<8; ef++){
        int e = 16*(8*eh + ef) + r;
        bf16x8 vb = *(const bf16x8*)(Vt + e*64 + (((4*ks + g) ^ (e&7)) << 3));
        oacc[ef]   = __builtin_amdgcn_mfma_f32_16x16x32_bf16(pa0, vb, oacc[ef],   0,0,0);
        oacc[8+ef] = __builtin_amdgcn_mfma_f32_16x16x32_bf16(pa1, vb, oacc[8+ef], 0,0,0);
      }
    }
    __builtin_amdgcn_s_setprio(0);
    __syncthreads();
  }

  // ---- Phase 2: Os = PV, coalesced u-multiply ----
  size_t growbase = rowbase + n0;
  #pragma unroll
  for (int rr=0; rr<2; rr++)
    #pragma unroll
    for (int ef=0; ef<8; ef++)
      #pragma unroll
      for (int reg=0; reg<4; reg++)
        Os[(32*rgp + 16*rr + 4*g + reg)*264 + 16*(8*eh+ef) + r] = f2b(oacc[rr*8+ef][reg]);
  __syncthreads();
  #pragma unroll
  for (int i=0;i<8;i++){
    int chunk = i*512 + tid;
    int row = chunk >> 5, c = chunk & 31;
    bf16x8 uvv = *(const bf16x8*)(u + (growbase + row)*D_ + c*8);
    bf16x8 ov  = *(const bf16x8*)(Os + row*264 + c*8);
    bf16x8 res;
    #pragma unroll
    for (int e=0;e<8;e++)
      ((bf16*)&res)[e] = f2b(b2f(((bf16*)&ov)[e]) * b2f(((bf16*)&uvv)[e]));
    *(bf16x8*)(Os + row*264 + c*8) = res;
  }
  __syncthreads();

  // ---- Os @ W2: kc-outer; wave w owns cols {16w..+15} and {128+16w..+15} ----
  f32x4 acc2[2][8];
  #pragma unroll
  for (int c2=0;c2<2;c2++)
    #pragma unroll
    for (int i=0;i<8;i++) acc2[c2][i] = (f32x4){0.f,0.f,0.f,0.f};
  __builtin_amdgcn_s_setprio(1);
  #pragma unroll
  for (int kc=0; kc<8; kc++){
    bf16x8 a0[8];
    #pragma unroll
    for (int i=0;i<8;i++)
      a0[i] = *(const bf16x8*)(Os + (16*i + r)*264 + kc*32 + g*8);
    #pragma unroll
    for (int chf=0; chf<2; chf++){
      bf16x8 wfr = *(const bf16x8*)(W2t + (size_t)(128*chf + 16*w + r)*256 + kc*32 + g*8);
      #pragma unroll
      for (int i=0;i<8;i++)
        acc2[chf][i] = __builtin_amdgcn_mfma_f32_16x16x32_bf16(a0[i], wfr, acc2[chf][i], 0,0,0);
    }
  }
  __builtin_amdgcn_s_setprio(0);

  // ---- epilogue (wave-owns-cols): residual RMW on bf16 hb ----
  #pragma unroll
  for (int chf=0; chf<2; chf++){
    int col = 128*chf + 16*w + r;
    float bv = bias[col];
    if (mode == 0) {
      #pragma unroll
      for (int i=0;i<8;i++){
        #pragma unroll
        for (int reg=0; reg<4; reg++){
          size_t row = growbase + 16*i + 4*g + reg;
          float hv = b2f(hb[row*D_ + col]) + acc2[chf][i][reg] + bv;
          hb[row*D_ + col] = f2b(hv);
          float ssum = hv*hv;
          ssum += __shfl_xor(ssum,1); ssum += __shfl_xor(ssum,2);
          ssum += __shfl_xor(ssum,4); ssum += __shfl_xor(ssum,8);
          if (r == 0) atomicAdd(rms1 + row, ssum);
        }
      }
    } else {
      float psum = 0.f;
      #pragma unroll
      for (int i=0;i<8;i++){
        #pragma unroll
        for (int reg=0; reg<4; reg++){
          size_t row = growbase + 16*i + 4*g + reg;
          float hv = b2f(hb[row*D_ + col]) + acc2[chf][i][reg] + bv;
          outb[row*D_ + col] = hv;
          float cv = fmaxf(hv, 1e-6f);
          psum += cv*cv*cv;
        }
      }
      psum += __shfl_xor(psum,16); psum += __shfl_xor(psum,32);
      if (g == 0) atomicAdd(pooled_raw + b*D_ + col, psum);
    }
  }
}

// ---------------- emb: pooled=cbrt(raw/T); emb = norm(pooled@We+be) ----------------
__global__ __launch_bounds__(256) void emb_kernel(const float* pooled_raw, const float* We,
      const float* be, float* out) {
  __shared__ float pr[D_];
  __shared__ float red[256];
  int b = blockIdx.x, j = threadIdx.x;
  pr[j] = cbrtf(pooled_raw[b*D_+j] * (1.f/T_));
  __syncthreads();
  float acc = be[j];
  for (int kk=0;kk<D_;kk++) acc += pr[kk]*We[kk*D_+j];
  red[j] = acc*acc;
  __syncthreads();
  for (int off=128; off>0; off>>=1){
    if (j<off) red[j]+=red[j+off];
    __syncthreads();
  }
  out[b*D_+j] = acc * rsqrtf(red[0]);
}

extern "C" void kernel_launch(void* const* d_in, const int* in_sizes, int n_in,
                              void* d_out, int out_size, void* d_ws, size_t ws_size,
                              hipStream_t stream) {
  const float* x         = (const float*)d_in[0];
  const float* pe_scale  = (const float*)d_in[1];
  const float* W_in      = (const float*)d_in[2];
  const float* b_in      = (const float*)d_in[3];
  const float* norm_scale= (const float*)d_in[4];
  const float* W1        = (const float*)d_in[5];
  const float* b1        = (const float*)d_in[6];
  const float* gamma     = (const float*)d_in[7];
  const float* beta      = (const float*)d_in[8];
  const float* W2        = (const float*)d_in[9];
  const float* b2        = (const float*)d_in[10];
  const float* We        = (const float*)d_in[11];
  const float* be        = (const float*)d_in[12];

  char* ws = (char*)d_ws;
  bf16*  hb      = (bf16*)(ws);                       // 33,554,432 B (bf16 residual)
  bf16*  u       = (bf16*)(ws + 33554432);            // 33,554,432 B
  bf16*  Vtg     = (bf16*)(ws + 67108864);            // 33,554,432 B
  bf16*  basebuf = (bf16*)(ws + 100663296);           // 16,777,216 B
  bf16*  q       = (bf16*)(ws + 117440512);           // 16,777,216 B
  bf16*  kbuf    = (bf16*)(ws + 134217728);           // 16,777,216 B
  float* pe_tab  = (float*)(ws + 150994944);          //     49,152 B
  float* rs_tab  = (float*)(ws + 151044096);          //    131,072 B
  float* rc_tab  = (float*)(ws + 151175168);          //    131,072 B
  float* pooled_raw = (float*)(ws + 151306240);       //    131,072 B
  float* rms0    = (float*)(ws + 151437312);          //    262,144 B
  float* rms1    = (float*)(ws + 151699456);          //    262,144 B
  bf16*  W1t     = (bf16*)(ws + 151961600);           //    655,360 B
  bf16*  W2t     = (bf16*)(ws + 152616960);           //    262,144 B

  tables_kernel<<<T_, 64, 0, stream>>>(pe_scale, pe_tab, rs_tab, rc_tab);
  prep_kernel<<<1280, 256, 0, stream>>>(W1, W2, W1t, W2t);
  init_kernel<<<BT_/256, 256, 0, stream>>>(rms1, pooled_raw);
  embed_kernel<<<BT_/8, 256, 0, stream>>>(x, pe_tab, W_in, b_in, rms0, hb);
  float* outb = (float*)d_out + B_*D_;
  for (int l=0; l<L_; l++) {
    gemm1_mfma<<<BT_/128*5, 256, 0, stream>>>(hb, W1t + (size_t)l*640*D_, b1 + l*640,
        l ? rms1 : rms0, norm_scale, l, u, Vtg, basebuf);
    qk_kernel<<<BT_/2, 256, 0, stream>>>(basebuf, gamma, beta, l, rs_tab, rc_tab, q, kbuf);
    attn_gemm2_fused<<<B_*4, 512, 0, stream>>>(q, kbuf, Vtg, u,
        W2t + (size_t)l*D_*D_, b2 + l*D_, l, rms1, pooled_raw, outb, hb);
  }
  emb_kernel<<<B_, 256, 0, stream>>>(pooled_raw, We, be, (float*)d_out);
}